// Round 1
// baseline (791.082 us; speedup 1.0000x reference)
//
#include <hip/hip_runtime.h>

#define NN 100000
#define NE 1000000
#define HID 64

// ---------------------------------------------------------------------------
// Kernel 1: deg[c] += ew[e] for all edges (self-loop +1 folded into dinv).
// ---------------------------------------------------------------------------
__global__ __launch_bounds__(256) void deg_kernel(const int* __restrict__ col,
                                                  const float* __restrict__ ew,
                                                  float* __restrict__ deg) {
    int e = blockIdx.x * 256 + threadIdx.x;
    if (e < NE) atomicAdd(&deg[col[e]], ew[e]);
}

// ---------------------------------------------------------------------------
// Kernel 2: dinv[i] = rsqrt(deg[i] + 1)   (deg+1 >= 1 so always > 0)
// ---------------------------------------------------------------------------
__global__ __launch_bounds__(256) void dinv_kernel(float* __restrict__ deg) {
    int i = blockIdx.x * 256 + threadIdx.x;
    if (i < NN) deg[i] = rsqrtf(deg[i] + 1.0f);
}

// ---------------------------------------------------------------------------
// Kernel 3: edge aggregation. One wave (64 lanes) per edge; lane i owns hid i.
// xw recomputed on the fly from x[row] (3 / 18 FMAs) against register-held W
// columns — avoids materializing xw (51 MB) and the 512 MB random gather.
// ---------------------------------------------------------------------------
__global__ __launch_bounds__(256) void agg_kernel(const int* __restrict__ ei,
                                                  const float* __restrict__ ew,
                                                  const float* __restrict__ dinv,
                                                  const float* __restrict__ ux,
                                                  const float* __restrict__ mx,
                                                  const float* __restrict__ Wu,
                                                  const float* __restrict__ Wm,
                                                  float* __restrict__ agg_u,
                                                  float* __restrict__ agg_m) {
    const int lane = threadIdx.x & 63;
    const int wid = (blockIdx.x * blockDim.x + threadIdx.x) >> 6;
    const int nw = (gridDim.x * blockDim.x) >> 6;

    // register-held W columns for this lane
    const float wu0 = Wu[0 * HID + lane];
    const float wu1 = Wu[1 * HID + lane];
    const float wu2 = Wu[2 * HID + lane];
    float wm[18];
#pragma unroll
    for (int k = 0; k < 18; k++) wm[k] = Wm[k * HID + lane];

    for (int e = wid; e < NE; e += nw) {
        const int row = ei[e];
        const int col = ei[NE + e];
        const float w = ew[e];
        const float nrm = dinv[row] * w * dinv[col];

        const float* u = ux + row * 3;
        float xu = fmaf(u[2], wu2, fmaf(u[1], wu1, u[0] * wu0));
        atomicAdd(&agg_u[col * HID + lane], nrm * xu);

        const float* m = mx + row * 18;
        float xm = 0.f;
#pragma unroll
        for (int k = 0; k < 18; k++) xm = fmaf(m[k], wm[k], xm);
        atomicAdd(&agg_m[col * HID + lane], nrm * xm);
    }
}

// ---------------------------------------------------------------------------
// Kernel 4: self-loop term + biases + 2-layer MLP. 128 threads = 1 node.
// Thread j holds W1[:,j] in 128 VGPRs; h broadcast from LDS via float4.
// ---------------------------------------------------------------------------
__global__ __launch_bounds__(128) void mlp_kernel(const float* __restrict__ ux,
                                                  const float* __restrict__ mx,
                                                  const float* __restrict__ dinv,
                                                  const float* __restrict__ agg_u,
                                                  const float* __restrict__ agg_m,
                                                  const float* __restrict__ Wu,
                                                  const float* __restrict__ bu,
                                                  const float* __restrict__ Wm,
                                                  const float* __restrict__ bm,
                                                  const float* __restrict__ W1,
                                                  const float* __restrict__ b1,
                                                  const float* __restrict__ W2,
                                                  const float* __restrict__ b2,
                                                  float* __restrict__ out) {
    const int j = threadIdx.x;        // 0..127: output feature of layer 1
    const bool is_u = (j < 64);       // wave 0 = user half, wave 1 = movie half
    const int jm = j & 63;

    // per-thread input-proj column (wave-uniform branch: no divergence)
    float wcol[18];
    if (is_u) {
        wcol[0] = Wu[jm];
        wcol[1] = Wu[HID + jm];
        wcol[2] = Wu[2 * HID + jm];
    } else {
#pragma unroll
        for (int k = 0; k < 18; k++) wcol[k] = Wm[k * HID + jm];
    }

    // W1 column j resident in VGPRs, loaded once per block
    float w1col[128];
#pragma unroll
    for (int k = 0; k < 128; k++) w1col[k] = W1[k * 128 + j];

    const float bias_j = is_u ? bu[jm] : bm[jm];
    const float b1j = b1[j];
    const float w2j = W2[j];
    const float b2v = b2[0];

    __shared__ float hbuf[128];
    __shared__ float red[2];

    for (int node = blockIdx.x; node < NN; node += gridDim.x) {
        const float di = dinv[node];
        const float di2 = di * di;

        // on-the-fly xw for the self-loop contribution
        float xw;
        if (is_u) {
            const float* u = ux + node * 3;
            xw = fmaf(u[2], wcol[2], fmaf(u[1], wcol[1], u[0] * wcol[0]));
        } else {
            const float* m = mx + node * 18;
            xw = 0.f;
#pragma unroll
            for (int k = 0; k < 18; k++) xw = fmaf(m[k], wcol[k], xw);
        }

        const float agg = is_u ? agg_u[node * HID + jm] : agg_m[node * HID + jm];
        const float h = fmaf(di2, xw, agg) + bias_j;
        hbuf[j] = h;
        __syncthreads();

        // layer 1: out1[j] = relu(b1[j] + sum_k h[k] * W1[k][j])
        float acc = b1j;
#pragma unroll
        for (int k4 = 0; k4 < 32; k4++) {
            const float4 hv = ((const float4*)hbuf)[k4];  // same-addr broadcast
            acc = fmaf(hv.x, w1col[4 * k4 + 0], acc);
            acc = fmaf(hv.y, w1col[4 * k4 + 1], acc);
            acc = fmaf(hv.z, w1col[4 * k4 + 2], acc);
            acc = fmaf(hv.w, w1col[4 * k4 + 3], acc);
        }

        // layer 2 partial + block reduce (2 waves of 64)
        float o = fmaxf(acc, 0.f) * w2j;
#pragma unroll
        for (int off = 32; off > 0; off >>= 1) o += __shfl_down(o, off);
        if ((j & 63) == 0) red[j >> 6] = o;
        __syncthreads();
        if (j == 0) out[node] = red[0] + red[1] + b2v;
    }
}

// ---------------------------------------------------------------------------
extern "C" void kernel_launch(void* const* d_in, const int* in_sizes, int n_in,
                              void* d_out, int out_size, void* d_ws, size_t ws_size,
                              hipStream_t stream) {
    const float* ux = (const float*)d_in[0];   // user_x  [N,3]
    const float* mx = (const float*)d_in[1];   // movie_x [N,18]
    const int* ei = (const int*)d_in[2];       // edge_index [2,E]
    const float* ew = (const float*)d_in[3];   // edge_attr [E]
    const float* Wu = (const float*)d_in[4];   // [3,64]
    const float* bu = (const float*)d_in[5];   // [64]
    const float* Wm = (const float*)d_in[6];   // [18,64]
    const float* bm = (const float*)d_in[7];   // [64]
    const float* W1 = (const float*)d_in[8];   // [128,128]
    const float* b1 = (const float*)d_in[9];   // [128]
    const float* W2 = (const float*)d_in[10];  // [128,1]
    const float* b2 = (const float*)d_in[11];  // [1]
    float* out = (float*)d_out;

    float* agg_u = (float*)d_ws;                    // N*64 floats
    float* agg_m = agg_u + (size_t)NN * HID;        // N*64 floats
    float* deg = agg_m + (size_t)NN * HID;          // N floats (becomes dinv)
    const size_t zero_bytes = ((size_t)NN * HID * 2 + NN) * sizeof(float);
    hipMemsetAsync(d_ws, 0, zero_bytes, stream);

    deg_kernel<<<(NE + 255) / 256, 256, 0, stream>>>(ei + NE, ew, deg);
    dinv_kernel<<<(NN + 255) / 256, 256, 0, stream>>>(deg);
    agg_kernel<<<4096, 256, 0, stream>>>(ei, ew, deg, ux, mx, Wu, Wm, agg_u, agg_m);
    mlp_kernel<<<2048, 128, 0, stream>>>(ux, mx, deg, agg_u, agg_m, Wu, bu, Wm, bm,
                                         W1, b1, W2, b2, out);
}

// Round 2
// 778.464 us; speedup vs baseline: 1.0162x; 1.0162x over previous
//
#include <hip/hip_runtime.h>

#define NN 100000
#define NE 1000000
#define HID 64
#define CHUNK 1024
#define NB 98  // ceil(NN / CHUNK)

// ===========================================================================
// Sorted (CSR) path
// ===========================================================================

// K1: deg[c] += ew[e]; hist[c] += 1. 800 KB of L2-resident atomics.
__global__ __launch_bounds__(256) void deg_hist_kernel(const int* __restrict__ col,
                                                       const float* __restrict__ ew,
                                                       float* __restrict__ deg,
                                                       int* __restrict__ hist) {
    int e = blockIdx.x * 256 + threadIdx.x;
    if (e < NE) {
        int c = col[e];
        atomicAdd(&deg[c], ew[e]);
        atomicAdd(&hist[c], 1);
    }
}

// K2: dinv[i] = rsqrt(deg[i] + 1)  (self-loop weight 1 folded; always > 0)
__global__ __launch_bounds__(256) void dinv_kernel(float* __restrict__ deg) {
    int i = blockIdx.x * 256 + threadIdx.x;
    if (i < NN) deg[i] = rsqrtf(deg[i] + 1.0f);
}

// K3a: per-chunk sums of hist -> partials[NB]
__global__ __launch_bounds__(256) void scan_p1(const int* __restrict__ hist,
                                               int* __restrict__ partials) {
    int base = blockIdx.x * CHUNK;
    int t = threadIdx.x;
    int sum = 0;
#pragma unroll
    for (int i = 0; i < 4; i++) {
        int idx = base + t * 4 + i;
        if (idx < NN) sum += hist[idx];
    }
    __shared__ int s[256];
    s[t] = sum;
    __syncthreads();
    for (int off = 128; off > 0; off >>= 1) {
        if (t < off) s[t] += s[t + off];
        __syncthreads();
    }
    if (t == 0) partials[blockIdx.x] = s[0];
}

// K3b: exclusive scan of partials (single block, NB <= 128)
__global__ __launch_bounds__(128) void scan_p2(int* __restrict__ partials, int nb) {
    __shared__ int s[128];
    int t = threadIdx.x;
    int v = (t < nb) ? partials[t] : 0;
    s[t] = v;
    __syncthreads();
    for (int off = 1; off < 128; off <<= 1) {
        int x = (t >= off) ? s[t - off] : 0;
        __syncthreads();
        s[t] += x;
        __syncthreads();
    }
    if (t < nb) partials[t] = s[t] - v;  // exclusive
}

// K3c: in-place hist -> exclusive offsets (cur)
__global__ __launch_bounds__(256) void scan_p3(int* __restrict__ cur,
                                               const int* __restrict__ partials) {
    int base = blockIdx.x * CHUNK;
    int t = threadIdx.x;
    int v[4];
#pragma unroll
    for (int i = 0; i < 4; i++) {
        int idx = base + t * 4 + i;
        v[i] = (idx < NN) ? cur[idx] : 0;
    }
    int tot = v[0] + v[1] + v[2] + v[3];
    __shared__ int s[256];
    s[t] = tot;
    __syncthreads();
    for (int off = 1; off < 256; off <<= 1) {
        int x = (t >= off) ? s[t - off] : 0;
        __syncthreads();
        s[t] += x;
        __syncthreads();
    }
    int exc = s[t] - tot;  // exclusive prefix of this thread within chunk
    int o = partials[blockIdx.x] + exc;
#pragma unroll
    for (int i = 0; i < 4; i++) {
        int idx = base + t * 4 + i;
        if (idx < NN) cur[idx] = o;
        o += v[i];
    }
}

// K4: scatter edges into CSR payload (8 B/edge). After this, cur[c] holds the
// INCLUSIVE offset (end) for col c; start = cur[c-1] (0 for c==0).
__global__ __launch_bounds__(256) void scatter_kernel(const int* __restrict__ ei,
                                                      const float* __restrict__ ew,
                                                      int* __restrict__ cur,
                                                      int2* __restrict__ payload) {
    int e = blockIdx.x * 256 + threadIdx.x;
    if (e < NE) {
        int c = ei[NE + e];
        int slot = atomicAdd(&cur[c], 1);
        payload[slot] = make_int2(ei[e], __float_as_int(ew[e]));
    }
}

// K5: segmented reduce. One wave per col, lane = hid. Recomputes x@W on the
// fly (W columns in registers), folds the self-loop, writes agg once.
__global__ __launch_bounds__(256) void reduce_kernel(const int2* __restrict__ payload,
                                                     const int* __restrict__ cur,
                                                     const float* __restrict__ dinv,
                                                     const float* __restrict__ ux,
                                                     const float* __restrict__ mx,
                                                     const float* __restrict__ Wu,
                                                     const float* __restrict__ Wm,
                                                     float* __restrict__ agg_u,
                                                     float* __restrict__ agg_m) {
    const int lane = threadIdx.x & 63;
    const int wid0 = (blockIdx.x * blockDim.x + threadIdx.x) >> 6;
    const int nw = (gridDim.x * blockDim.x) >> 6;

    const float wu0 = Wu[lane];
    const float wu1 = Wu[HID + lane];
    const float wu2 = Wu[2 * HID + lane];
    float wm[18];
#pragma unroll
    for (int k = 0; k < 18; k++) wm[k] = Wm[k * HID + lane];

    for (int c = wid0; c < NN; c += nw) {
        const int end = cur[c];
        const int start = (c > 0) ? cur[c - 1] : 0;
        const float dc = dinv[c];

        float au = 0.f, am = 0.f;
        if (start < end) {
            int2 p = payload[start];
            for (int i = start; i < end; i++) {
                int2 pn = (i + 1 < end) ? payload[i + 1] : p;  // prefetch
                const int row = p.x;
                const float w = __int_as_float(p.y);
                const float nrm = dinv[row] * w * dc;
                const float* u = ux + row * 3;
                const float* m = mx + row * 18;
                float xu = fmaf(u[2], wu2, fmaf(u[1], wu1, u[0] * wu0));
                float xm = 0.f;
#pragma unroll
                for (int k = 0; k < 18; k++) xm = fmaf(m[k], wm[k], xm);
                au = fmaf(nrm, xu, au);
                am = fmaf(nrm, xm, am);
                p = pn;
            }
        }
        // self-loop: dinv[c]^2 * (x[c] @ W)
        const float d2 = dc * dc;
        const float* u = ux + c * 3;
        const float* m = mx + c * 18;
        float xu = fmaf(u[2], wu2, fmaf(u[1], wu1, u[0] * wu0));
        float xm = 0.f;
#pragma unroll
        for (int k = 0; k < 18; k++) xm = fmaf(m[k], wm[k], xm);
        au = fmaf(d2, xu, au);
        am = fmaf(d2, xm, am);

        agg_u[c * HID + lane] = au;
        agg_m[c * HID + lane] = am;
    }
}

// K6: bias + 2-layer MLP, 4 nodes per block-iteration for ILP.
__global__ __launch_bounds__(128) void mlp4_kernel(const float* __restrict__ agg_u,
                                                   const float* __restrict__ agg_m,
                                                   const float* __restrict__ bu,
                                                   const float* __restrict__ bm,
                                                   const float* __restrict__ W1,
                                                   const float* __restrict__ b1,
                                                   const float* __restrict__ W2,
                                                   const float* __restrict__ b2,
                                                   float* __restrict__ out) {
    const int j = threadIdx.x;
    const bool is_u = (j < 64);
    const int jm = j & 63;

    float w1col[128];
#pragma unroll
    for (int k = 0; k < 128; k++) w1col[k] = W1[k * 128 + j];

    const float bias_j = is_u ? bu[jm] : bm[jm];
    const float b1j = b1[j];
    const float w2j = W2[j];
    const float b2v = b2[0];

    __shared__ float hbuf[4][128];
    __shared__ float red[2][4];

    for (int base = blockIdx.x * 4; base < NN; base += gridDim.x * 4) {
#pragma unroll
        for (int n = 0; n < 4; n++) {
            const float hv = is_u ? agg_u[(size_t)(base + n) * HID + jm]
                                  : agg_m[(size_t)(base + n) * HID + jm];
            hbuf[n][j] = hv + bias_j;
        }
        __syncthreads();

        float a0 = b1j, a1 = b1j, a2 = b1j, a3 = b1j;
#pragma unroll
        for (int k4 = 0; k4 < 32; k4++) {
            const float4 h0 = ((const float4*)hbuf[0])[k4];
            const float4 h1 = ((const float4*)hbuf[1])[k4];
            const float4 h2 = ((const float4*)hbuf[2])[k4];
            const float4 h3 = ((const float4*)hbuf[3])[k4];
            const float w0 = w1col[4 * k4 + 0], w1 = w1col[4 * k4 + 1];
            const float w2 = w1col[4 * k4 + 2], w3 = w1col[4 * k4 + 3];
            a0 = fmaf(h0.x, w0, a0); a0 = fmaf(h0.y, w1, a0);
            a0 = fmaf(h0.z, w2, a0); a0 = fmaf(h0.w, w3, a0);
            a1 = fmaf(h1.x, w0, a1); a1 = fmaf(h1.y, w1, a1);
            a1 = fmaf(h1.z, w2, a1); a1 = fmaf(h1.w, w3, a1);
            a2 = fmaf(h2.x, w0, a2); a2 = fmaf(h2.y, w1, a2);
            a2 = fmaf(h2.z, w2, a2); a2 = fmaf(h2.w, w3, a2);
            a3 = fmaf(h3.x, w0, a3); a3 = fmaf(h3.y, w1, a3);
            a3 = fmaf(h3.z, w2, a3); a3 = fmaf(h3.w, w3, a3);
        }

        float o[4] = {fmaxf(a0, 0.f) * w2j, fmaxf(a1, 0.f) * w2j,
                      fmaxf(a2, 0.f) * w2j, fmaxf(a3, 0.f) * w2j};
#pragma unroll
        for (int n = 0; n < 4; n++) {
            float v = o[n];
#pragma unroll
            for (int off = 32; off > 0; off >>= 1) v += __shfl_down(v, off);
            if ((j & 63) == 0) red[j >> 6][n] = v;
        }
        __syncthreads();
        if (j < 4) out[base + j] = red[0][j] + red[1][j] + b2v;
        __syncthreads();
    }
}

// ===========================================================================
// Fallback path (round-1 atomic version) — used only if ws_size is too small.
// ===========================================================================
__global__ __launch_bounds__(256) void deg_kernel(const int* __restrict__ col,
                                                  const float* __restrict__ ew,
                                                  float* __restrict__ deg) {
    int e = blockIdx.x * 256 + threadIdx.x;
    if (e < NE) atomicAdd(&deg[col[e]], ew[e]);
}

__global__ __launch_bounds__(256) void agg_kernel(const int* __restrict__ ei,
                                                  const float* __restrict__ ew,
                                                  const float* __restrict__ dinv,
                                                  const float* __restrict__ ux,
                                                  const float* __restrict__ mx,
                                                  const float* __restrict__ Wu,
                                                  const float* __restrict__ Wm,
                                                  float* __restrict__ agg_u,
                                                  float* __restrict__ agg_m) {
    const int lane = threadIdx.x & 63;
    const int wid = (blockIdx.x * blockDim.x + threadIdx.x) >> 6;
    const int nw = (gridDim.x * blockDim.x) >> 6;
    const float wu0 = Wu[lane], wu1 = Wu[HID + lane], wu2 = Wu[2 * HID + lane];
    float wm[18];
#pragma unroll
    for (int k = 0; k < 18; k++) wm[k] = Wm[k * HID + lane];
    for (int e = wid; e < NE; e += nw) {
        const int row = ei[e];
        const int col = ei[NE + e];
        const float nrm = dinv[row] * ew[e] * dinv[col];
        const float* u = ux + row * 3;
        float xu = fmaf(u[2], wu2, fmaf(u[1], wu1, u[0] * wu0));
        atomicAdd(&agg_u[col * HID + lane], nrm * xu);
        const float* m = mx + row * 18;
        float xm = 0.f;
#pragma unroll
        for (int k = 0; k < 18; k++) xm = fmaf(m[k], wm[k], xm);
        atomicAdd(&agg_m[col * HID + lane], nrm * xm);
    }
}

__global__ __launch_bounds__(128) void mlp_kernel(const float* __restrict__ ux,
                                                  const float* __restrict__ mx,
                                                  const float* __restrict__ dinv,
                                                  const float* __restrict__ agg_u,
                                                  const float* __restrict__ agg_m,
                                                  const float* __restrict__ Wu,
                                                  const float* __restrict__ bu,
                                                  const float* __restrict__ Wm,
                                                  const float* __restrict__ bm,
                                                  const float* __restrict__ W1,
                                                  const float* __restrict__ b1,
                                                  const float* __restrict__ W2,
                                                  const float* __restrict__ b2,
                                                  float* __restrict__ out) {
    const int j = threadIdx.x;
    const bool is_u = (j < 64);
    const int jm = j & 63;
    float wcol[18];
    if (is_u) {
        wcol[0] = Wu[jm]; wcol[1] = Wu[HID + jm]; wcol[2] = Wu[2 * HID + jm];
    } else {
#pragma unroll
        for (int k = 0; k < 18; k++) wcol[k] = Wm[k * HID + jm];
    }
    float w1col[128];
#pragma unroll
    for (int k = 0; k < 128; k++) w1col[k] = W1[k * 128 + j];
    const float bias_j = is_u ? bu[jm] : bm[jm];
    const float b1j = b1[j], w2j = W2[j], b2v = b2[0];
    __shared__ float hbuf[128];
    __shared__ float red[2];
    for (int node = blockIdx.x; node < NN; node += gridDim.x) {
        const float di = dinv[node];
        const float di2 = di * di;
        float xw;
        if (is_u) {
            const float* u = ux + node * 3;
            xw = fmaf(u[2], wcol[2], fmaf(u[1], wcol[1], u[0] * wcol[0]));
        } else {
            const float* m = mx + node * 18;
            xw = 0.f;
#pragma unroll
            for (int k = 0; k < 18; k++) xw = fmaf(m[k], wcol[k], xw);
        }
        const float agg = is_u ? agg_u[node * HID + jm] : agg_m[node * HID + jm];
        hbuf[j] = fmaf(di2, xw, agg) + bias_j;
        __syncthreads();
        float acc = b1j;
#pragma unroll
        for (int k4 = 0; k4 < 32; k4++) {
            const float4 hv = ((const float4*)hbuf)[k4];
            acc = fmaf(hv.x, w1col[4 * k4 + 0], acc);
            acc = fmaf(hv.y, w1col[4 * k4 + 1], acc);
            acc = fmaf(hv.z, w1col[4 * k4 + 2], acc);
            acc = fmaf(hv.w, w1col[4 * k4 + 3], acc);
        }
        float o = fmaxf(acc, 0.f) * w2j;
#pragma unroll
        for (int off = 32; off > 0; off >>= 1) o += __shfl_down(o, off);
        if ((j & 63) == 0) red[j >> 6] = o;
        __syncthreads();
        if (j == 0) out[node] = red[0] + red[1] + b2v;
        __syncthreads();
    }
}

// ===========================================================================
extern "C" void kernel_launch(void* const* d_in, const int* in_sizes, int n_in,
                              void* d_out, int out_size, void* d_ws, size_t ws_size,
                              hipStream_t stream) {
    const float* ux = (const float*)d_in[0];
    const float* mx = (const float*)d_in[1];
    const int* ei = (const int*)d_in[2];
    const float* ew = (const float*)d_in[3];
    const float* Wu = (const float*)d_in[4];
    const float* bu = (const float*)d_in[5];
    const float* Wm = (const float*)d_in[6];
    const float* bm = (const float*)d_in[7];
    const float* W1 = (const float*)d_in[8];
    const float* b1 = (const float*)d_in[9];
    const float* W2 = (const float*)d_in[10];
    const float* b2 = (const float*)d_in[11];
    float* out = (float*)d_out;

    char* ws = (char*)d_ws;
    float* agg_u = (float*)ws;                                   // 25.6 MB
    float* agg_m = (float*)(ws + 25600000);                      // 25.6 MB
    float* deg   = (float*)(ws + 51200000);                      // 400 KB (-> dinv)
    int*   cur   = (int*)(ws + 51600000);                        // 400 KB (hist -> offs)
    int*   partials = (int*)(ws + 52000000);                     // 512 B
    int2*  payload  = (int2*)(ws + 52000512);                    // 8 MB
    const size_t need_sorted = 52000512 + (size_t)NE * 8;        // 60.0 MB

    if (ws_size >= need_sorted) {
        // deg + cur are adjacent: one 800 KB memset
        hipMemsetAsync(deg, 0, 2 * NN * sizeof(float), stream);
        deg_hist_kernel<<<(NE + 255) / 256, 256, 0, stream>>>(ei + NE, ew, deg, cur);
        dinv_kernel<<<(NN + 255) / 256, 256, 0, stream>>>(deg);
        scan_p1<<<NB, 256, 0, stream>>>(cur, partials);
        scan_p2<<<1, 128, 0, stream>>>(partials, NB);
        scan_p3<<<NB, 256, 0, stream>>>(cur, partials);
        scatter_kernel<<<(NE + 255) / 256, 256, 0, stream>>>(ei, ew, cur, payload);
        reduce_kernel<<<4096, 256, 0, stream>>>(payload, cur, deg, ux, mx, Wu, Wm,
                                                agg_u, agg_m);
        mlp4_kernel<<<2048, 128, 0, stream>>>(agg_u, agg_m, bu, bm, W1, b1, W2, b2, out);
    } else {
        // round-1 fallback
        hipMemsetAsync(d_ws, 0, (size_t)NN * HID * 2 * 4 + NN * 4, stream);
        deg_kernel<<<(NE + 255) / 256, 256, 0, stream>>>(ei + NE, ew, deg);
        dinv_kernel<<<(NN + 255) / 256, 256, 0, stream>>>(deg);
        agg_kernel<<<4096, 256, 0, stream>>>(ei, ew, deg, ux, mx, Wu, Wm, agg_u, agg_m);
        mlp_kernel<<<2048, 128, 0, stream>>>(ux, mx, deg, agg_u, agg_m, Wu, bu, Wm, bm,
                                             W1, b1, W2, b2, out);
    }
}

// Round 3
// 681.130 us; speedup vs baseline: 1.1614x; 1.1429x over previous
//
#include <hip/hip_runtime.h>

#define NN 100000
#define NE 1000000
#define CHUNK 1024
#define NB 98       // ceil(NN / CHUNK)
#define SDIM 24     // padded s row: [0..2]=user agg, [3..20]=movie agg, 21..23 pad

// ---------------------------------------------------------------------------
// K1: hist[c] += 1 per edge (int atomics into 400 KB, L2-resident)
// ---------------------------------------------------------------------------
__global__ __launch_bounds__(256) void hist_kernel(const int* __restrict__ col,
                                                   int* __restrict__ hist) {
    int e = blockIdx.x * 256 + threadIdx.x;
    if (e < NE) atomicAdd(&hist[col[e]], 1);
}

// ---------------------------------------------------------------------------
// K2a/b/c: exclusive scan of hist -> CSR offsets (in place in `cur`)
// ---------------------------------------------------------------------------
__global__ __launch_bounds__(256) void scan_p1(const int* __restrict__ hist,
                                               int* __restrict__ partials) {
    int base = blockIdx.x * CHUNK;
    int t = threadIdx.x;
    int sum = 0;
#pragma unroll
    for (int i = 0; i < 4; i++) {
        int idx = base + t * 4 + i;
        if (idx < NN) sum += hist[idx];
    }
    __shared__ int s[256];
    s[t] = sum;
    __syncthreads();
    for (int off = 128; off > 0; off >>= 1) {
        if (t < off) s[t] += s[t + off];
        __syncthreads();
    }
    if (t == 0) partials[blockIdx.x] = s[0];
}

__global__ __launch_bounds__(128) void scan_p2(int* __restrict__ partials, int nb) {
    __shared__ int s[128];
    int t = threadIdx.x;
    int v = (t < nb) ? partials[t] : 0;
    s[t] = v;
    __syncthreads();
    for (int off = 1; off < 128; off <<= 1) {
        int x = (t >= off) ? s[t - off] : 0;
        __syncthreads();
        s[t] += x;
        __syncthreads();
    }
    if (t < nb) partials[t] = s[t] - v;  // exclusive
}

__global__ __launch_bounds__(256) void scan_p3(int* __restrict__ cur,
                                               const int* __restrict__ partials) {
    int base = blockIdx.x * CHUNK;
    int t = threadIdx.x;
    int v[4];
#pragma unroll
    for (int i = 0; i < 4; i++) {
        int idx = base + t * 4 + i;
        v[i] = (idx < NN) ? cur[idx] : 0;
    }
    int tot = v[0] + v[1] + v[2] + v[3];
    __shared__ int s[256];
    s[t] = tot;
    __syncthreads();
    for (int off = 1; off < 256; off <<= 1) {
        int x = (t >= off) ? s[t - off] : 0;
        __syncthreads();
        s[t] += x;
        __syncthreads();
    }
    int exc = s[t] - tot;
    int o = partials[blockIdx.x] + exc;
#pragma unroll
    for (int i = 0; i < 4; i++) {
        int idx = base + t * 4 + i;
        if (idx < NN) cur[idx] = o;
        o += v[i];
    }
}

// ---------------------------------------------------------------------------
// K3: scatter edges into CSR payload (row, ew) — 8 B/edge. After this,
// cur[c] = inclusive end offset for col c; start = cur[c-1] (0 for c==0).
// ---------------------------------------------------------------------------
__global__ __launch_bounds__(256) void scatter_kernel(const int* __restrict__ ei,
                                                      const float* __restrict__ ew,
                                                      int* __restrict__ cur,
                                                      int2* __restrict__ payload) {
    int e = blockIdx.x * 256 + threadIdx.x;
    if (e < NE) {
        int c = ei[NE + e];
        int slot = atomicAdd(&cur[c], 1);
        payload[slot] = make_int2(ei[e], __float_as_int(ew[e]));
    }
}

// ---------------------------------------------------------------------------
// K4: dinv from CSR segment sums (no atomics). deg = 1 (self-loop) + sum(w).
// ---------------------------------------------------------------------------
__global__ __launch_bounds__(256) void dinv_csr_kernel(const int2* __restrict__ payload,
                                                       const int* __restrict__ cur,
                                                       float* __restrict__ dinv) {
    int c = blockIdx.x * 256 + threadIdx.x;
    if (c >= NN) return;
    const int end = cur[c];
    const int start = (c > 0) ? cur[c - 1] : 0;
    float sum = 1.0f;
    for (int i = start; i < end; i++) sum += __int_as_float(payload[i].y);
    dinv[c] = rsqrtf(sum);
}

// ---------------------------------------------------------------------------
// K5: aggregate RAW features (aggregate-then-transform). Thread-per-col,
// 21-float register accumulator. s[c] = dc*(sum_e dinv[row]*w*x[row] + dc*x[c]).
// ---------------------------------------------------------------------------
__global__ __launch_bounds__(256) void agg_s_kernel(const int2* __restrict__ payload,
                                                    const int* __restrict__ cur,
                                                    const float* __restrict__ dinv,
                                                    const float* __restrict__ ux,
                                                    const float* __restrict__ mx,
                                                    float* __restrict__ s) {
    int c = blockIdx.x * 256 + threadIdx.x;
    if (c >= NN) return;
    const int end = cur[c];
    const int start = (c > 0) ? cur[c - 1] : 0;

    float su0 = 0.f, su1 = 0.f, su2 = 0.f;
    float sm[18];
#pragma unroll
    for (int k = 0; k < 18; k++) sm[k] = 0.f;

    for (int i = start; i < end; i++) {
        const int2 p = payload[i];
        const int row = p.x;
        const float dw = dinv[row] * __int_as_float(p.y);
        const float* u = ux + (size_t)row * 3;
        su0 = fmaf(dw, u[0], su0);
        su1 = fmaf(dw, u[1], su1);
        su2 = fmaf(dw, u[2], su2);
        const float2* m2 = (const float2*)(mx + (size_t)row * 18);  // 8B-aligned
#pragma unroll
        for (int k = 0; k < 9; k++) {
            const float2 mv = m2[k];
            sm[2 * k]     = fmaf(dw, mv.x, sm[2 * k]);
            sm[2 * k + 1] = fmaf(dw, mv.y, sm[2 * k + 1]);
        }
    }

    // self-loop folded: + dc * x[c], then scale everything by dc
    const float dc = dinv[c];
    const float* uc = ux + (size_t)c * 3;
    su0 = fmaf(dc, uc[0], su0);
    su1 = fmaf(dc, uc[1], su1);
    su2 = fmaf(dc, uc[2], su2);
    const float* mc = mx + (size_t)c * 18;
#pragma unroll
    for (int k = 0; k < 18; k++) sm[k] = fmaf(dc, mc[k], sm[k]);

    float* so = s + (size_t)c * SDIM;
    so[0] = dc * su0;
    so[1] = dc * su1;
    so[2] = dc * su2;
#pragma unroll
    for (int k = 0; k < 18; k++) so[3 + k] = dc * sm[k];
}

// ---------------------------------------------------------------------------
// K6: transform + MLP. 128 threads; thread j owns W1[:,j] in VGPRs; h[j]
// computed on the fly from s (3 or 18 FMAs vs broadcast loads); 4 nodes/iter.
// ---------------------------------------------------------------------------
__global__ __launch_bounds__(128) void mlp_s_kernel(const float* __restrict__ s,
                                                    const float* __restrict__ Wu,
                                                    const float* __restrict__ bu,
                                                    const float* __restrict__ Wm,
                                                    const float* __restrict__ bm,
                                                    const float* __restrict__ W1,
                                                    const float* __restrict__ b1,
                                                    const float* __restrict__ W2,
                                                    const float* __restrict__ b2,
                                                    float* __restrict__ out) {
    const int j = threadIdx.x;
    const bool is_u = (j < 64);   // wave-uniform
    const int jm = j & 63;

    float wcol[18];
    if (is_u) {
        wcol[0] = Wu[jm];
        wcol[1] = Wu[64 + jm];
        wcol[2] = Wu[128 + jm];
    } else {
#pragma unroll
        for (int k = 0; k < 18; k++) wcol[k] = Wm[k * 64 + jm];
    }

    float w1col[128];
#pragma unroll
    for (int k = 0; k < 128; k++) w1col[k] = W1[k * 128 + j];

    const float bias_j = is_u ? bu[jm] : bm[jm];
    const float b1j = b1[j];
    const float w2j = W2[j];
    const float b2v = b2[0];

    __shared__ float hbuf[4][128];
    __shared__ float red[2][4];

    for (int base = blockIdx.x * 4; base < NN; base += gridDim.x * 4) {
#pragma unroll
        for (int n = 0; n < 4; n++) {
            const float* sp = s + (size_t)(base + n) * SDIM;
            float h = bias_j;
            if (is_u) {
                h = fmaf(sp[0], wcol[0], h);
                h = fmaf(sp[1], wcol[1], h);
                h = fmaf(sp[2], wcol[2], h);
            } else {
#pragma unroll
                for (int k = 0; k < 18; k++) h = fmaf(sp[3 + k], wcol[k], h);
            }
            hbuf[n][j] = h;
        }
        __syncthreads();

        float a0 = b1j, a1 = b1j, a2 = b1j, a3 = b1j;
#pragma unroll
        for (int k4 = 0; k4 < 32; k4++) {
            const float4 h0 = ((const float4*)hbuf[0])[k4];
            const float4 h1 = ((const float4*)hbuf[1])[k4];
            const float4 h2 = ((const float4*)hbuf[2])[k4];
            const float4 h3 = ((const float4*)hbuf[3])[k4];
            const float w0 = w1col[4 * k4 + 0], w1 = w1col[4 * k4 + 1];
            const float w2 = w1col[4 * k4 + 2], w3 = w1col[4 * k4 + 3];
            a0 = fmaf(h0.x, w0, a0); a0 = fmaf(h0.y, w1, a0);
            a0 = fmaf(h0.z, w2, a0); a0 = fmaf(h0.w, w3, a0);
            a1 = fmaf(h1.x, w0, a1); a1 = fmaf(h1.y, w1, a1);
            a1 = fmaf(h1.z, w2, a1); a1 = fmaf(h1.w, w3, a1);
            a2 = fmaf(h2.x, w0, a2); a2 = fmaf(h2.y, w1, a2);
            a2 = fmaf(h2.z, w2, a2); a2 = fmaf(h2.w, w3, a2);
            a3 = fmaf(h3.x, w0, a3); a3 = fmaf(h3.y, w1, a3);
            a3 = fmaf(h3.z, w2, a3); a3 = fmaf(h3.w, w3, a3);
        }

        float o[4] = {fmaxf(a0, 0.f) * w2j, fmaxf(a1, 0.f) * w2j,
                      fmaxf(a2, 0.f) * w2j, fmaxf(a3, 0.f) * w2j};
#pragma unroll
        for (int n = 0; n < 4; n++) {
            float v = o[n];
#pragma unroll
            for (int off = 32; off > 0; off >>= 1) v += __shfl_down(v, off);
            if ((j & 63) == 0) red[j >> 6][n] = v;
        }
        __syncthreads();
        if (j < 4) out[base + j] = red[0][j] + red[1][j] + b2v;
        __syncthreads();
    }
}

// ===========================================================================
extern "C" void kernel_launch(void* const* d_in, const int* in_sizes, int n_in,
                              void* d_out, int out_size, void* d_ws, size_t ws_size,
                              hipStream_t stream) {
    const float* ux = (const float*)d_in[0];   // user_x  [N,3]
    const float* mx = (const float*)d_in[1];   // movie_x [N,18]
    const int* ei = (const int*)d_in[2];       // edge_index [2,E]
    const float* ew = (const float*)d_in[3];   // edge_attr [E]
    const float* Wu = (const float*)d_in[4];   // [3,64]
    const float* bu = (const float*)d_in[5];   // [64]
    const float* Wm = (const float*)d_in[6];   // [18,64]
    const float* bm = (const float*)d_in[7];   // [64]
    const float* W1 = (const float*)d_in[8];   // [128,128]
    const float* b1 = (const float*)d_in[9];   // [128]
    const float* W2 = (const float*)d_in[10];  // [128,1]
    const float* b2 = (const float*)d_in[11];  // [1]
    float* out = (float*)d_out;

    char* ws = (char*)d_ws;
    float* s        = (float*)ws;                    // N*24*4 = 9.6 MB
    float* dinv     = (float*)(ws + 9600000);        // 400 KB
    int*   cur      = (int*)(ws + 10000000);         // 400 KB (hist -> offsets)
    int*   partials = (int*)(ws + 10400000);         // 512 B
    int2*  payload  = (int2*)(ws + 10400512);        // 8 MB
    // total ~18.4 MB (<< the 60 MB that fit in round 2)

    hipMemsetAsync(cur, 0, NN * sizeof(int), stream);
    hist_kernel<<<(NE + 255) / 256, 256, 0, stream>>>(ei + NE, cur);
    scan_p1<<<NB, 256, 0, stream>>>(cur, partials);
    scan_p2<<<1, 128, 0, stream>>>(partials, NB);
    scan_p3<<<NB, 256, 0, stream>>>(cur, partials);
    scatter_kernel<<<(NE + 255) / 256, 256, 0, stream>>>(ei, ew, cur, payload);
    dinv_csr_kernel<<<(NN + 255) / 256, 256, 0, stream>>>(payload, cur, dinv);
    agg_s_kernel<<<(NN + 255) / 256, 256, 0, stream>>>(payload, cur, dinv, ux, mx, s);
    mlp_s_kernel<<<2048, 128, 0, stream>>>(s, Wu, bu, Wm, bm, W1, b1, W2, b2, out);
}

// Round 4
// 296.500 us; speedup vs baseline: 2.6681x; 2.2972x over previous
//
#include <hip/hip_runtime.h>

#define NN 100000
#define NE 1000000
#define CHUNK 1024
#define NB 98       // ceil(NN / CHUNK)
#define SDIM 24     // padded s row: [0..2]=user agg, [3..20]=movie agg, 21..23 pad

// ---------------------------------------------------------------------------
// K1: hist[c] += 1 per edge (int atomics into 400 KB, L2-resident)
// ---------------------------------------------------------------------------
__global__ __launch_bounds__(256) void hist_kernel(const int* __restrict__ col,
                                                   int* __restrict__ hist) {
    int e = blockIdx.x * 256 + threadIdx.x;
    if (e < NE) atomicAdd(&hist[col[e]], 1);
}

// ---------------------------------------------------------------------------
// K2a/b/c: exclusive scan of hist -> CSR offsets (in place in `cur`)
// ---------------------------------------------------------------------------
__global__ __launch_bounds__(256) void scan_p1(const int* __restrict__ hist,
                                               int* __restrict__ partials) {
    int base = blockIdx.x * CHUNK;
    int t = threadIdx.x;
    int sum = 0;
#pragma unroll
    for (int i = 0; i < 4; i++) {
        int idx = base + t * 4 + i;
        if (idx < NN) sum += hist[idx];
    }
    __shared__ int s[256];
    s[t] = sum;
    __syncthreads();
    for (int off = 128; off > 0; off >>= 1) {
        if (t < off) s[t] += s[t + off];
        __syncthreads();
    }
    if (t == 0) partials[blockIdx.x] = s[0];
}

__global__ __launch_bounds__(128) void scan_p2(int* __restrict__ partials, int nb) {
    __shared__ int s[128];
    int t = threadIdx.x;
    int v = (t < nb) ? partials[t] : 0;
    s[t] = v;
    __syncthreads();
    for (int off = 1; off < 128; off <<= 1) {
        int x = (t >= off) ? s[t - off] : 0;
        __syncthreads();
        s[t] += x;
        __syncthreads();
    }
    if (t < nb) partials[t] = s[t] - v;  // exclusive
}

__global__ __launch_bounds__(256) void scan_p3(int* __restrict__ cur,
                                               const int* __restrict__ partials) {
    int base = blockIdx.x * CHUNK;
    int t = threadIdx.x;
    int v[4];
#pragma unroll
    for (int i = 0; i < 4; i++) {
        int idx = base + t * 4 + i;
        v[i] = (idx < NN) ? cur[idx] : 0;
    }
    int tot = v[0] + v[1] + v[2] + v[3];
    __shared__ int s[256];
    s[t] = tot;
    __syncthreads();
    for (int off = 1; off < 256; off <<= 1) {
        int x = (t >= off) ? s[t - off] : 0;
        __syncthreads();
        s[t] += x;
        __syncthreads();
    }
    int exc = s[t] - tot;
    int o = partials[blockIdx.x] + exc;
#pragma unroll
    for (int i = 0; i < 4; i++) {
        int idx = base + t * 4 + i;
        if (idx < NN) cur[idx] = o;
        o += v[i];
    }
}

// ---------------------------------------------------------------------------
// K3: scatter edges into CSR payload (row, ew) — 8 B/edge. After this,
// cur[c] = inclusive end offset for col c; start = cur[c-1] (0 for c==0).
// ---------------------------------------------------------------------------
__global__ __launch_bounds__(256) void scatter_kernel(const int* __restrict__ ei,
                                                      const float* __restrict__ ew,
                                                      int* __restrict__ cur,
                                                      int2* __restrict__ payload) {
    int e = blockIdx.x * 256 + threadIdx.x;
    if (e < NE) {
        int c = ei[NE + e];
        int slot = atomicAdd(&cur[c], 1);
        payload[slot] = make_int2(ei[e], __float_as_int(ew[e]));
    }
}

// ---------------------------------------------------------------------------
// K4: dinv from CSR segment sums (no atomics). deg = 1 (self-loop) + sum(w).
// ---------------------------------------------------------------------------
__global__ __launch_bounds__(256) void dinv_csr_kernel(const int2* __restrict__ payload,
                                                       const int* __restrict__ cur,
                                                       float* __restrict__ dinv) {
    int c = blockIdx.x * 256 + threadIdx.x;
    if (c >= NN) return;
    const int end = cur[c];
    const int start = (c > 0) ? cur[c - 1] : 0;
    float sum = 1.0f;
    for (int i = start; i < end; i++) sum += __int_as_float(payload[i].y);
    dinv[c] = rsqrtf(sum);
}

// ---------------------------------------------------------------------------
// K5: aggregate RAW features (aggregate-then-transform). Thread-per-col,
// 21-float register accumulator. s[c] = dc*(sum_e dinv[row]*w*x[row] + dc*x[c]).
// ---------------------------------------------------------------------------
__global__ __launch_bounds__(256) void agg_s_kernel(const int2* __restrict__ payload,
                                                    const int* __restrict__ cur,
                                                    const float* __restrict__ dinv,
                                                    const float* __restrict__ ux,
                                                    const float* __restrict__ mx,
                                                    float* __restrict__ s) {
    int c = blockIdx.x * 256 + threadIdx.x;
    if (c >= NN) return;
    const int end = cur[c];
    const int start = (c > 0) ? cur[c - 1] : 0;

    float su0 = 0.f, su1 = 0.f, su2 = 0.f;
    float sm[18];
#pragma unroll
    for (int k = 0; k < 18; k++) sm[k] = 0.f;

    for (int i = start; i < end; i++) {
        const int2 p = payload[i];
        const int row = p.x;
        const float dw = dinv[row] * __int_as_float(p.y);
        const float* u = ux + (size_t)row * 3;
        su0 = fmaf(dw, u[0], su0);
        su1 = fmaf(dw, u[1], su1);
        su2 = fmaf(dw, u[2], su2);
        const float2* m2 = (const float2*)(mx + (size_t)row * 18);  // 8B-aligned
#pragma unroll
        for (int k = 0; k < 9; k++) {
            const float2 mv = m2[k];
            sm[2 * k]     = fmaf(dw, mv.x, sm[2 * k]);
            sm[2 * k + 1] = fmaf(dw, mv.y, sm[2 * k + 1]);
        }
    }

    // self-loop folded: + dc * x[c], then scale everything by dc
    const float dc = dinv[c];
    const float* uc = ux + (size_t)c * 3;
    su0 = fmaf(dc, uc[0], su0);
    su1 = fmaf(dc, uc[1], su1);
    su2 = fmaf(dc, uc[2], su2);
    const float* mc = mx + (size_t)c * 18;
#pragma unroll
    for (int k = 0; k < 18; k++) sm[k] = fmaf(dc, mc[k], sm[k]);

    float* so = s + (size_t)c * SDIM;
    so[0] = dc * su0;
    so[1] = dc * su1;
    so[2] = dc * su2;
#pragma unroll
    for (int k = 0; k < 18; k++) so[3 + k] = dc * sm[k];
}

// ---------------------------------------------------------------------------
// K6: fuse the linear chain: M[21][128] = [Wu@W1_top ; Wm@W1_bot],
// b1p = b1 + bu@W1_top + bm@W1_bot. One block of 128 threads; thread j owns
// column j. Runs once per launch (~3 µs).
// ---------------------------------------------------------------------------
__global__ __launch_bounds__(128) void fuse_kernel(const float* __restrict__ Wu,
                                                   const float* __restrict__ bu,
                                                   const float* __restrict__ Wm,
                                                   const float* __restrict__ bm,
                                                   const float* __restrict__ W1,
                                                   const float* __restrict__ b1,
                                                   float* __restrict__ M,
                                                   float* __restrict__ b1p) {
    const int j = threadIdx.x;
    float w1c[128];
#pragma unroll
    for (int k = 0; k < 128; k++) w1c[k] = W1[k * 128 + j];

#pragma unroll
    for (int m = 0; m < 3; m++) {
        float acc = 0.f;
#pragma unroll
        for (int k = 0; k < 64; k++) acc = fmaf(Wu[m * 64 + k], w1c[k], acc);
        M[m * 128 + j] = acc;
    }
#pragma unroll
    for (int m = 0; m < 18; m++) {
        float acc = 0.f;
#pragma unroll
        for (int k = 0; k < 64; k++) acc = fmaf(Wm[m * 64 + k], w1c[64 + k], acc);
        M[(3 + m) * 128 + j] = acc;
    }
    float bp = b1[j];
#pragma unroll
    for (int k = 0; k < 64; k++) {
        bp = fmaf(bu[k], w1c[k], bp);
        bp = fmaf(bm[k], w1c[64 + k], bp);
    }
    b1p[j] = bp;
}

// ---------------------------------------------------------------------------
// K7: fused MLP. One wave per node; lane j holds M[:,j] and M[:,j+64] (42
// VGPRs). out[node] = relu(s·M + b1p) @ W2 + b2. No LDS tile, no syncthreads.
// ---------------------------------------------------------------------------
__global__ __launch_bounds__(256) void mlp_fused_kernel(const float* __restrict__ s,
                                                        const float* __restrict__ M,
                                                        const float* __restrict__ b1p,
                                                        const float* __restrict__ W2,
                                                        const float* __restrict__ b2,
                                                        float* __restrict__ out) {
    const int lane = threadIdx.x & 63;
    const int wid = (blockIdx.x * blockDim.x + threadIdx.x) >> 6;
    const int nw = (gridDim.x * blockDim.x) >> 6;

    float Ma[21], Mb[21];
#pragma unroll
    for (int m = 0; m < 21; m++) {
        Ma[m] = M[m * 128 + lane];
        Mb[m] = M[m * 128 + 64 + lane];
    }
    const float ba = b1p[lane], bb = b1p[64 + lane];
    const float w2a = W2[lane], w2b = W2[64 + lane];
    const float b2v = b2[0];

    for (int node = wid; node < NN; node += nw) {
        const float4* sp = (const float4*)(s + (size_t)node * SDIM);
        float sv[24];
        ((float4*)sv)[0] = sp[0];
        ((float4*)sv)[1] = sp[1];
        ((float4*)sv)[2] = sp[2];
        ((float4*)sv)[3] = sp[3];
        ((float4*)sv)[4] = sp[4];
        ((float4*)sv)[5] = sp[5];   // sv[21..23] = pad, unused

        float ha = ba, hb = bb;
#pragma unroll
        for (int m = 0; m < 21; m++) {
            ha = fmaf(sv[m], Ma[m], ha);
            hb = fmaf(sv[m], Mb[m], hb);
        }
        float o = fmaf(fmaxf(ha, 0.f), w2a, fmaxf(hb, 0.f) * w2b);
#pragma unroll
        for (int off = 32; off > 0; off >>= 1) o += __shfl_down(o, off);
        if (lane == 0) out[node] = o + b2v;
    }
}

// ===========================================================================
extern "C" void kernel_launch(void* const* d_in, const int* in_sizes, int n_in,
                              void* d_out, int out_size, void* d_ws, size_t ws_size,
                              hipStream_t stream) {
    const float* ux = (const float*)d_in[0];   // user_x  [N,3]
    const float* mx = (const float*)d_in[1];   // movie_x [N,18]
    const int* ei = (const int*)d_in[2];       // edge_index [2,E]
    const float* ew = (const float*)d_in[3];   // edge_attr [E]
    const float* Wu = (const float*)d_in[4];   // [3,64]
    const float* bu = (const float*)d_in[5];   // [64]
    const float* Wm = (const float*)d_in[6];   // [18,64]
    const float* bm = (const float*)d_in[7];   // [64]
    const float* W1 = (const float*)d_in[8];   // [128,128]
    const float* b1 = (const float*)d_in[9];   // [128]
    const float* W2 = (const float*)d_in[10];  // [128,1]
    const float* b2 = (const float*)d_in[11];  // [1]
    float* out = (float*)d_out;

    char* ws = (char*)d_ws;
    float* s        = (float*)ws;                    // N*24*4 = 9.6 MB
    float* dinv     = (float*)(ws + 9600000);        // 400 KB
    int*   cur      = (int*)(ws + 10000000);         // 400 KB (hist -> offsets)
    int*   partials = (int*)(ws + 10400000);         // 512 B
    float* M        = (float*)(ws + 10401024);       // 21*128*4 = 10752 B
    float* b1p      = (float*)(ws + 10411776);       // 512 B
    int2*  payload  = (int2*)(ws + 10412288);        // 8 MB
    // total ~18.4 MB

    hipMemsetAsync(cur, 0, NN * sizeof(int), stream);
    fuse_kernel<<<1, 128, 0, stream>>>(Wu, bu, Wm, bm, W1, b1, M, b1p);
    hist_kernel<<<(NE + 255) / 256, 256, 0, stream>>>(ei + NE, cur);
    scan_p1<<<NB, 256, 0, stream>>>(cur, partials);
    scan_p2<<<1, 128, 0, stream>>>(partials, NB);
    scan_p3<<<NB, 256, 0, stream>>>(cur, partials);
    scatter_kernel<<<(NE + 255) / 256, 256, 0, stream>>>(ei, ew, cur, payload);
    dinv_csr_kernel<<<(NN + 255) / 256, 256, 0, stream>>>(payload, cur, dinv);
    agg_s_kernel<<<(NN + 255) / 256, 256, 0, stream>>>(payload, cur, dinv, ux, mx, s);
    mlp_fused_kernel<<<2048, 256, 0, stream>>>(s, M, b1p, W2, b2, out);
}